// Round 9
// baseline (64843.176 us; speedup 1.0000x reference)
//
#include <hip/hip_runtime.h>

// Problem constants
#define T_STEPS 16384
#define CSTEPS  1024     // steps per Z chunk
#define NCHUNK  16
#define DMODEL  1024
#define HID     512      // per-direction hidden
#define G4      2048     // 4*HID gate rows
#define NC      16
#define NGEMMB  128      // GEMM producer blocks
#define RWAVES  256u     // recur waves (64 blocks x 4): recur_prog threshold

#define POLL_GUARD (1 << 16)   // MALL h-poll timeout (safety net only)
#define LDS_GUARD  (1 << 17)   // LDS flag-spin timeout

// ---------------- ws layout ----------------
static const size_t OFF_Z     = 0;             // 8,388,608 floats (32 MB)
static const size_t OFF_HF    = 8388608ull;
static const size_t OFF_HB    = 16777216ull;
static const size_t OFF_FEATS = 25165824ull;   // 262,144 floats
static const size_t FLOATS_TOTAL = 25427968ull;
static const size_t OFF_BP_B  = FLOATS_TOTAL * 4ull;   // 101,711,872
static const size_t OFF_P_B   = OFF_BP_B + 262144ull;
static const size_t OFF_EX_B  = OFF_P_B + 262144ull;   // 16 KB: exf[1024]+exb[1024]
static const size_t OFF_CTR_B = OFF_EX_B + 16384ull;   // 1 KB counters
static const size_t NEED_B    = OFF_CTR_B + 1024ull;

// fast transcendentals (v_exp_f32-based; abs err ~1e-7, saturation-safe)
__device__ __forceinline__ float sigm_fast(float x) { return 1.0f / (1.0f + __expf(-x)); }
__device__ __forceinline__ float tanh_fast(float x) { return 1.0f - 2.0f / (__expf(2.0f * x) + 1.0f); }

// =====================================================================
// Fused kernel, 256 blocks x 256 threads (cooperative).
// Role by bid%8: 0 -> recur dir0 (g=bid>>3), 1 -> recur dir1,
// 2..5 -> GEMM (128 blocks), 6..7 -> exit.
// 96KB LDS pad forces 1 block/CU (kills CU-sharing slow mode, r8).
//
// Recurrence: WAVE-AUTONOMOUS engines. Wave w of block g owns units
// [16g+4w, 16g+4w+4) = 16 gate rows; lane l holds K-quarter (l>>4) of
// row (l&15) in 128 VGPRs. Per step: wave polls h-quarter w from MALL
// (tagged u64, 2/lane), relays via LDS h_sh[par] + qtag flag; spins on
// the 4 flags; dot = 128 FMA + shfl_xor(16)+shfl_xor(32); gates via
// shfl; lanes 0-3 publish their units. No intra-block barrier, no
// wave-0 relay. Wave skew bounded to 1 step by flag dataflow; parity
// double-buffering covers it. Guards + deadf => no hangs ever.
// =====================================================================
__global__ __launch_bounds__(256, 1) void fused_kernel(
    const float* __restrict__ seq,
    const float* __restrict__ wih_f, const float* __restrict__ bih_f, const float* __restrict__ bhh_f,
    const float* __restrict__ wih_b, const float* __restrict__ bih_b, const float* __restrict__ bhh_b,
    const float* __restrict__ whh_f, const float* __restrict__ whh_b,
    const float* __restrict__ h0, const float* __restrict__ c0,
    float* __restrict__ hf, float* __restrict__ hb,
    float* __restrict__ Zbuf,
    unsigned long long* __restrict__ exf,
    unsigned int* __restrict__ gemm_done, unsigned int* __restrict__ recur_prog)
{
    const int bid = blockIdx.x;
    const int tid = threadIdx.x;
    const int pk  = bid & 7;

    // ---- occupancy limiter: 96KB LDS pad -> exactly 1 block/CU ----
    __shared__ float pad_lds[24576];
    if (gemm_done == recur_prog) {   // never true at runtime; not provable at compile time
        ((volatile float*)pad_lds)[tid] = 1.0f;
    }

    if (pk < 2) {
        // ---------------- recurrence role ----------------
        const int dir = pk;
        const int g   = bid >> 3;            // 0..31
        const float* whh = dir ? whh_b : whh_f;
        float* hout      = dir ? hb : hf;
        unsigned long long* ex = dir ? (exf + 1024) : exf;

        const int w    = tid >> 6, lane = tid & 63;
        const int rl   = lane & 15;          // row index within wave's 16 rows
        const int q    = lane >> 4;          // K-quarter handled by this lane
        const int Gg   = rl >> 2;            // gate index (0=i,1=f,2=g,3=o)
        const int v    = rl & 3;             // unit-within-wave
        const int unit = 16 * g + 4 * w + v; // global hidden unit (for rl-lanes)
        const int R    = 512 * Gg + unit;    // gate row owned by this lane

        // lane holds K-quarter q of gate row R
        float wreg[128];
        {
            const float* src = &whh[(size_t)R * HID + q * 128];
            #pragma unroll
            for (int j = 0; j < 32; ++j) {
                float4 x = *(const float4*)&src[j * 4];
                wreg[j*4+0]=x.x; wreg[j*4+1]=x.y; wreg[j*4+2]=x.z; wreg[j*4+3]=x.w;
            }
        }

        __shared__ __align__(16) float h_sh[2][512];   // parity h relay
        __shared__ int qtag[2][4];                      // per-quarter seq flags
        __shared__ int deadf;

        if (tid < 8) ((volatile int*)qtag)[tid] = -1;
        if (tid == 8) deadf = 0;
        __syncthreads();   // one-time init barrier only

        volatile int* vtag  = (volatile int*)qtag;
        volatile int* vdead = (volatile int*)&deadf;

        float cst = 0.f;
        if (lane < 4) cst = c0[dir * HID + unit];

        int dead = 0;
        const float* Zd = Zbuf + (size_t)dir * 2 * CSTEPS * G4;
        float zr_cur = 0.f, zr_pref = 0.f;

        for (int s = 0; s < T_STEPS; ++s) {
            const int par = s & 1;

            // ---- chunk gate + Z load (per wave; Z used by lanes q==0) ----
            if ((s & (CSTEPS - 1)) == 0) {
                const int cg = s >> 10;
                int guard = 0; unsigned int gd;
                for (;;) {
                    gd = __hip_atomic_load(&gemm_done[cg], __ATOMIC_RELAXED,
                                           __HIP_MEMORY_SCOPE_AGENT);
                    if (gd >= (unsigned)NGEMMB) break;
                    __builtin_amdgcn_s_sleep(2);
                    if (++guard > (1 << 16)) { dead = 1; break; }
                }
                if (lane < 16) {
                    const int rr = dir ? (1023 - (s & 1023)) : (s & 1023);
                    zr_cur = __hip_atomic_load(
                        &Zd[((size_t)((s >> 10) & 1) * CSTEPS + rr) * G4 + R],
                        __ATOMIC_RELAXED, __HIP_MEMORY_SCOPE_AGENT);
                }
            }

            // ---- acquire h-quarter w (MALL poll or h0), relay to LDS ----
            {
                const int i0 = 128 * w + 2 * lane;   // this wave's quarter slice
                float hv0, hv1;
                if (s == 0) {
                    hv0 = h0[dir * HID + i0];
                    hv1 = h0[dir * HID + i0 + 1];
                } else {
                    const int base = par * 512 + i0;
                    const unsigned long long want = (unsigned long long)(unsigned)s;
                    unsigned long long v0, v1;
                    int guard = 0;
                    for (;;) {
                        v0 = __hip_atomic_load(&ex[base],     __ATOMIC_RELAXED, __HIP_MEMORY_SCOPE_AGENT);
                        v1 = __hip_atomic_load(&ex[base + 1], __ATOMIC_RELAXED, __HIP_MEMORY_SCOPE_AGENT);
                        if (((v0 >> 32) == want) & ((v1 >> 32) == want)) break;
                        if ((++guard & 63) == 0) {
                            if (*vdead) { dead = 1; break; }
                            if (guard > POLL_GUARD) { *vdead = 1; dead = 1; break; }
                        }
                    }
                    union { unsigned int ui; float f; } ca, cb;
                    ca.ui = (unsigned int)v0; cb.ui = (unsigned int)v1;
                    hv0 = ca.f; hv1 = cb.f;
                }
                if (dead) { *vdead = 1; break; }
                h_sh[par][i0]     = hv0;
                h_sh[par][i0 + 1] = hv1;
                asm volatile("s_waitcnt lgkmcnt(0)" ::: "memory");
                if (lane == 0) vtag[par * 4 + w] = s;
            }

            // ---- wait all 4 quarters of this parity ----
            {
                int guard = 0;
                for (;;) {
                    int c0f = vtag[par * 4 + 0];
                    int c1f = vtag[par * 4 + 1];
                    int c2f = vtag[par * 4 + 2];
                    int c3f = vtag[par * 4 + 3];
                    if ((c0f == s) & (c1f == s) & (c2f == s) & (c3f == s)) break;
                    if ((++guard & 63) == 0) {
                        if (*vdead) { dead = 1; break; }
                        if (guard > LDS_GUARD) { *vdead = 1; dead = 1; break; }
                    }
                }
                if (dead) break;
                asm volatile("" ::: "memory");   // no hoisting h reads above spin
            }

            // ---- dot: this lane's 128-K quarter of its gate row ----
            float a0 = 0.f, a1 = 0.f, a2 = 0.f, a3 = 0.f;
            {
                const float4* h4 = (const float4*)&h_sh[par][q * 128];
                #pragma unroll
                for (int j = 0; j < 8; ++j) {
                    float4 h_0 = h4[4*j+0], h_1 = h4[4*j+1], h_2 = h4[4*j+2], h_3 = h4[4*j+3];
                    a0 += wreg[16*j+ 0]*h_0.x + wreg[16*j+ 1]*h_0.y + wreg[16*j+ 2]*h_0.z + wreg[16*j+ 3]*h_0.w;
                    a1 += wreg[16*j+ 4]*h_1.x + wreg[16*j+ 5]*h_1.y + wreg[16*j+ 6]*h_1.z + wreg[16*j+ 7]*h_1.w;
                    a2 += wreg[16*j+ 8]*h_2.x + wreg[16*j+ 9]*h_2.y + wreg[16*j+10]*h_2.z + wreg[16*j+11]*h_2.w;
                    a3 += wreg[16*j+12]*h_3.x + wreg[16*j+13]*h_3.y + wreg[16*j+14]*h_3.z + wreg[16*j+15]*h_3.w;
                }
            }
            float acc = (a0 + a1) + (a2 + a3);
            if (q == 0) acc += zr_cur;           // fold Z once per row

            // Z prefetch for next step (within chunk)
            if (lane < 16 && ((s + 1) & (CSTEPS - 1)) != 0) {
                const int sn = s + 1;
                const int rr = dir ? (1023 - (sn & 1023)) : (sn & 1023);
                zr_pref = __hip_atomic_load(
                    &Zd[((size_t)((sn >> 10) & 1) * CSTEPS + rr) * G4 + R],
                    __ATOMIC_RELAXED, __HIP_MEMORY_SCOPE_AGENT);
            }

            // ---- complete row dot across the 4 K-quarters (in-wave) ----
            acc += __shfl_xor(acc, 16, 64);
            acc += __shfl_xor(acc, 32, 64);      // all lanes: full rv(rl)

            // ---- gates + state + publish (lanes 0..3 own the 4 units) ----
            float a = (Gg == 2) ? tanh_fast(acc) : sigm_fast(acc);
            float ig = __shfl(a,  v,      64);
            float fg = __shfl(a,  4 + v,  64);
            float gg = __shfl(a,  8 + v,  64);
            float og = __shfl(a, 12 + v,  64);
            if (lane < 4) {
                float cn = fg * cst + ig * gg;
                cst = cn;
                float hn = og * tanh_fast(cn);
                union { float f; unsigned int ui; } cv; cv.f = hn;
                unsigned long long pv =
                    ((unsigned long long)(unsigned)(s + 1) << 32) | (unsigned long long)cv.ui;
                __hip_atomic_store(&ex[((s + 1) & 1) * 512 + unit], pv,
                                   __ATOMIC_RELAXED, __HIP_MEMORY_SCOPE_AGENT);
                const int t = dir ? (T_STEPS - 1 - s) : s;
                hout[(size_t)t * HID + unit] = hn;
            }
            if (lane < 16) zr_cur = zr_pref;

            if ((s & (CSTEPS - 1)) == (CSTEPS - 1) && lane == 0)
                __hip_atomic_fetch_add(&recur_prog[s >> 10], 1u, __ATOMIC_RELAXED,
                                       __HIP_MEMORY_SCOPE_AGENT);   // per-wave
        }
        if (dead) *vdead = 1;
    } else if (pk < 6) {
        // ---------------- GEMM producer role (128 blocks) ----------------
        const int gb = (pk - 2) * 32 + (bid >> 3);   // 0..127
        __shared__ __align__(16) float As[16][68];
        __shared__ __align__(16) float Bs[16][68];
        const int lr = tid >> 2, ls = tid & 3, tx = tid & 15, ty = tid >> 4;

        for (int cc = 0; cc < NCHUNK; ++cc) {
            if (cc >= 2 && tid == 0) {          // ring backpressure (sleepy spin)
                int guard = 0; unsigned int rp;
                for (;;) {
                    rp = __hip_atomic_load(&recur_prog[cc - 2], __ATOMIC_RELAXED,
                                           __HIP_MEMORY_SCOPE_AGENT);
                    if (rp >= RWAVES) break;    // all 256 recur waves done
                    __builtin_amdgcn_s_sleep(16);
                    if (++guard > (1 << 14)) break;
                }
            }
            __syncthreads();

            for (int tix = gb; tix < 2 * 16 * 32; tix += NGEMMB) {
                const int dr  = tix >> 9;
                const int rem = tix & 511;
                const int mt  = rem >> 5;
                const int nt  = rem & 31;
                const int t0  = dr ? (T_STEPS - (cc + 1) * CSTEPS) : (cc * CSTEPS);
                const float* W  = dr ? wih_b : wih_f;
                const float* bi = dr ? bih_b : bih_f;
                const float* bh = dr ? bhh_b : bhh_f;
                float* Zt = Zbuf + (size_t)(dr * 2 + (cc & 1)) * CSTEPS * G4;

                float acc[4][4] = {};
                for (int k0 = 0; k0 < DMODEL; k0 += 16) {
                    float4 av = *(const float4*)&seq[(size_t)(t0 + mt*64 + lr) * DMODEL + k0 + ls*4];
                    float4 bv = *(const float4*)&W[(size_t)(nt*64 + lr) * DMODEL + k0 + ls*4];
                    __syncthreads();
                    As[ls*4+0][lr]=av.x; As[ls*4+1][lr]=av.y; As[ls*4+2][lr]=av.z; As[ls*4+3][lr]=av.w;
                    Bs[ls*4+0][lr]=bv.x; Bs[ls*4+1][lr]=bv.y; Bs[ls*4+2][lr]=bv.z; Bs[ls*4+3][lr]=bv.w;
                    __syncthreads();
                    #pragma unroll
                    for (int k = 0; k < 16; ++k) {
                        float4 a = *(const float4*)&As[k][ty * 4];
                        float4 b = *(const float4*)&Bs[k][tx * 4];
                        acc[0][0]+=a.x*b.x; acc[0][1]+=a.x*b.y; acc[0][2]+=a.x*b.z; acc[0][3]+=a.x*b.w;
                        acc[1][0]+=a.y*b.x; acc[1][1]+=a.y*b.y; acc[1][2]+=a.y*b.z; acc[1][3]+=a.y*b.w;
                        acc[2][0]+=a.z*b.x; acc[2][1]+=a.z*b.y; acc[2][2]+=a.z*b.z; acc[2][3]+=a.z*b.w;
                        acc[3][0]+=a.w*b.x; acc[3][1]+=a.w*b.y; acc[3][2]+=a.w*b.z; acc[3][3]+=a.w*b.w;
                    }
                }
                float4 b4  = *(const float4*)&bi[nt * 64 + tx * 4];
                float4 c4v = *(const float4*)&bh[nt * 64 + tx * 4];
                float bx=b4.x+c4v.x, by=b4.y+c4v.y, bz=b4.z+c4v.z, bw_=b4.w+c4v.w;
                #pragma unroll
                for (int i = 0; i < 4; ++i) {
                    float4 o;
                    o.x=acc[i][0]+bx; o.y=acc[i][1]+by; o.z=acc[i][2]+bz; o.w=acc[i][3]+bw_;
                    *(float4*)&Zt[(size_t)(mt*64 + ty*4 + i) * G4 + nt*64 + tx*4] = o;
                }
            }
            __threadfence();                    // drain Z before signaling
            __syncthreads();
            if (tid == 0)
                __hip_atomic_fetch_add(&gemm_done[cc], 1u, __ATOMIC_RELEASE,
                                       __HIP_MEMORY_SCOPE_AGENT);
        }
    }
    // pk 6,7: exit immediately
}

// =====================================================================
__global__ __launch_bounds__(256) void feats_kernel(
    const float* __restrict__ hf, const float* __restrict__ hb,
    const float* __restrict__ wlin, const float* __restrict__ blin,
    float* __restrict__ feats)
{
    const int t = blockIdx.x;
    __shared__ __align__(16) float hl[1024];
    const int tid = threadIdx.x;
    {
        const float* src = (tid < 128) ? &hf[(size_t)t * HID + tid * 4]
                                       : &hb[(size_t)t * HID + (tid - 128) * 4];
        *(float4*)&hl[tid * 4] = *(const float4*)src;
    }
    __syncthreads();
    const int c = tid >> 4, p = tid & 15;
    float s = 0.0f;
    #pragma unroll
    for (int j = 0; j < 16; ++j) {
        float4 h4 = *(const float4*)&hl[p * 4 + j * 64];
        float4 w4 = *(const float4*)&wlin[(size_t)c * 1024 + p * 4 + j * 64];
        s += h4.x*w4.x + h4.y*w4.y + h4.z*w4.z + h4.w*w4.w;
    }
    s += __shfl_down(s, 8, 16);
    s += __shfl_down(s, 4, 16);
    s += __shfl_down(s, 2, 16);
    s += __shfl_down(s, 1, 16);
    if (p == 0) feats[t * NC + c] = s + blin[c];
}

// =====================================================================
__global__ __launch_bounds__(64) void viterbi_kernel(
    const float* __restrict__ feats, const float* __restrict__ trans,
    unsigned char* __restrict__ bp, float* __restrict__ out,
    unsigned int* __restrict__ bT)
{
    __shared__ __align__(16) float fl[4096];
    __shared__ __align__(16) float fvs[16];
    const int l = threadIdx.x;
    float tr[16];
    if (l < 16) {
        #pragma unroll
        for (int j = 0; j < 16; ++j) tr[j] = trans[l * 16 + j];
    }
    float fv = 0.0f;
    for (int cb = 0; cb < 64; ++cb) {
        #pragma unroll
        for (int j = 0; j < 16; ++j)
            *(float4*)&fl[j * 256 + l * 4] =
                *(const float4*)&feats[cb * 4096 + j * 256 + l * 4];
        __syncthreads();
        if (l < 16) {
            for (int k = 0; k < 256; ++k) {
                float m = __shfl(fv, 0, 16) + tr[0];
                int bi = 0;
                #pragma unroll
                for (int j = 1; j < 16; ++j) {
                    float sc = __shfl(fv, j, 16) + tr[j];
                    if (sc > m) { m = sc; bi = j; }   // strict > = first max
                }
                bp[(size_t)(cb * 256 + k) * 16 + l] = (unsigned char)bi;
                fv = m + fl[k * 16 + l];
            }
        }
        __syncthreads();
    }
    if (l < 16) fvs[l] = fv;
    __syncthreads();
    if (l == 0) {
        float best = fvs[0]; int bi = 0;
        #pragma unroll
        for (int j = 1; j < 16; ++j) if (fvs[j] > best) { best = fvs[j]; bi = j; }
        out[0] = best;
        out[1 + T_STEPS] = (float)bi;
        *bT = (unsigned int)bi;
    }
}

// =====================================================================
__global__ __launch_bounds__(64) void maps_kernel(
    const unsigned char* __restrict__ bp, unsigned char* __restrict__ P)
{
    const int j = blockIdx.x;
    const int l = threadIdx.x;
    __shared__ __align__(16) unsigned char lb[4096];
    __shared__ __align__(16) unsigned char lp[4096];
    #pragma unroll
    for (int i = 0; i < 4; ++i)
        *(uint4*)&lb[i * 1024 + l * 16] = *(const uint4*)&bp[(size_t)j * 4096 + i * 1024 + l * 16];
    __syncthreads();
    if (l < 16) {
        int cur = l;
        for (int k = 255; k >= 0; --k) {
            cur = lb[k * 16 + cur];
            lp[k * 16 + l] = (unsigned char)cur;
        }
    }
    __syncthreads();
    #pragma unroll
    for (int i = 0; i < 4; ++i)
        *(uint4*)&P[(size_t)j * 4096 + i * 1024 + l * 16] = *(const uint4*)&lp[i * 1024 + l * 16];
}

// =====================================================================
__global__ __launch_bounds__(64) void path_kernel(
    const unsigned char* __restrict__ P, const unsigned int* __restrict__ bT,
    float* __restrict__ out)
{
    const int j = blockIdx.x;
    const int l = threadIdx.x;
    int e = (int)(*bT);
    for (int i = 63; i > j; --i) e = P[(size_t)i * 4096 + e];
    for (int k = l; k < 256; k += 64)
        out[1 + j * 256 + k] = (float)P[(size_t)j * 4096 + k * 16 + e];
}

__global__ void fb_kernel(float* out, int n, float v0) {
    int i = blockIdx.x * 256 + threadIdx.x;
    if (i < n) out[i] = (i == 0) ? v0 : 0.0f;
}

extern "C" void kernel_launch(void* const* d_in, const int* in_sizes, int n_in,
                              void* d_out, int out_size, void* d_ws, size_t ws_size,
                              hipStream_t stream) {
    const float* seq   = (const float*)d_in[0];
    const float* h0    = (const float*)d_in[1];
    const float* c0    = (const float*)d_in[2];
    const float* wih_f = (const float*)d_in[3];
    const float* whh_f = (const float*)d_in[4];
    const float* bih_f = (const float*)d_in[5];
    const float* bhh_f = (const float*)d_in[6];
    const float* wih_b = (const float*)d_in[7];
    const float* whh_b = (const float*)d_in[8];
    const float* bih_b = (const float*)d_in[9];
    const float* bhh_b = (const float*)d_in[10];
    const float* wlin  = (const float*)d_in[11];
    const float* blin  = (const float*)d_in[12];
    const float* trans = (const float*)d_in[13];
    float* out = (float*)d_out;

    if (ws_size < NEED_B) {
        fb_kernel<<<(out_size + 255) / 256, 256, 0, stream>>>(out, out_size, -(float)ws_size);
        return;
    }

    float* wsf = (float*)d_ws;
    float* Zbuf  = wsf + OFF_Z;
    float* hf    = wsf + OFF_HF;
    float* hb    = wsf + OFF_HB;
    float* feats = wsf + OFF_FEATS;
    unsigned char* bp = (unsigned char*)d_ws + OFF_BP_B;
    unsigned char* P  = (unsigned char*)d_ws + OFF_P_B;
    unsigned long long* exf = (unsigned long long*)((char*)d_ws + OFF_EX_B);
    unsigned int* ctr = (unsigned int*)((char*)d_ws + OFF_CTR_B);
    unsigned int* gemm_done  = ctr;          // [16]
    unsigned int* recur_prog = ctr + 16;     // [16]
    unsigned int* bT         = ctr + 32;

    // zero exchange tags + counters each call (replay determinism)
    hipMemsetAsync((void*)exf, 0, 16384 + 1024, stream);

    {
        void* args[] = { (void*)&seq,
                         (void*)&wih_f, (void*)&bih_f, (void*)&bhh_f,
                         (void*)&wih_b, (void*)&bih_b, (void*)&bhh_b,
                         (void*)&whh_f, (void*)&whh_b,
                         (void*)&h0, (void*)&c0,
                         (void*)&hf, (void*)&hb, (void*)&Zbuf,
                         (void*)&exf,
                         (void*)&gemm_done, (void*)&recur_prog };
        hipError_t e = hipLaunchCooperativeKernel(
            reinterpret_cast<void*>(fused_kernel), dim3(256), dim3(256),
            args, 0, stream);
        if (e != hipSuccess) {
            fused_kernel<<<256, 256, 0, stream>>>(
                seq, wih_f, bih_f, bhh_f, wih_b, bih_b, bhh_b,
                whh_f, whh_b, h0, c0, hf, hb, Zbuf, exf,
                gemm_done, recur_prog);
        }
    }

    feats_kernel<<<16384, 256, 0, stream>>>(hf, hb, wlin, blin, feats);
    viterbi_kernel<<<1, 64, 0, stream>>>(feats, trans, bp, out, bT);
    maps_kernel<<<64, 64, 0, stream>>>(bp, P);
    path_kernel<<<64, 64, 0, stream>>>(P, bT, out);
}

// Round 10
// 43076.419 us; speedup vs baseline: 1.5053x; 1.5053x over previous
//
#include <hip/hip_runtime.h>

// Problem constants
#define T_STEPS 16384
#define CSTEPS  1024     // steps per Z chunk
#define NCHUNK  16
#define DMODEL  1024
#define HID     512      // per-direction hidden
#define G4      2048     // 4*HID gate rows
#define NC      16
#define NGEMMB  128      // GEMM producer blocks

#define POLL_GUARD (1 << 16)   // h-poll timeout -> dead (safety net only)

// ---------------- ws layout ----------------
static const size_t OFF_Z     = 0;             // 8,388,608 floats (32 MB)
static const size_t OFF_HF    = 8388608ull;
static const size_t OFF_HB    = 16777216ull;
static const size_t OFF_FEATS = 25165824ull;   // 262,144 floats
static const size_t FLOATS_TOTAL = 25427968ull;
static const size_t OFF_BP_B  = FLOATS_TOTAL * 4ull;   // 101,711,872
static const size_t OFF_P_B   = OFF_BP_B + 262144ull;
static const size_t OFF_EX_B  = OFF_P_B + 262144ull;   // 16 KB: exf[1024]+exb[1024]
static const size_t OFF_CTR_B = OFF_EX_B + 16384ull;   // 1 KB counters
static const size_t NEED_B    = OFF_CTR_B + 1024ull;

// fast transcendentals (v_exp_f32-based; abs err ~1e-7, saturation-safe)
__device__ __forceinline__ float sigm_fast(float x) { return 1.0f / (1.0f + __expf(-x)); }
__device__ __forceinline__ float tanh_fast(float x) { return 1.0f - 2.0f / (__expf(2.0f * x) + 1.0f); }

// =====================================================================
// Fused kernel, 256 blocks x 256 threads (cooperative). [r8 structure]
// Role by bid%8: 0 -> recur dir0 (g=bid>>3), 1 -> recur dir1,
// 2..5 -> GEMM (128 blocks), 6..7 -> exit.
// 96KB LDS pad forces 1 block/CU. Barrier-free recurrence: wave-private
// h slices; waves 1-3 post dot-partials to p_lds + LDS seq flags;
// wave 0 reduces, applies gates, publishes tagged u64 {step|f32} h via
// relaxed agent atomics (MALL). Parity double-buffering bounds
// runahead; deadf flag => no hangs.
// =====================================================================
__global__ __launch_bounds__(256, 1) void fused_kernel(
    const float* __restrict__ seq,
    const float* __restrict__ wih_f, const float* __restrict__ bih_f, const float* __restrict__ bhh_f,
    const float* __restrict__ wih_b, const float* __restrict__ bih_b, const float* __restrict__ bhh_b,
    const float* __restrict__ whh_f, const float* __restrict__ whh_b,
    const float* __restrict__ h0, const float* __restrict__ c0,
    float* __restrict__ hf, float* __restrict__ hb,
    float* __restrict__ Zbuf,
    unsigned long long* __restrict__ exf,
    unsigned int* __restrict__ gemm_done, unsigned int* __restrict__ recur_prog)
{
    const int bid = blockIdx.x;
    const int tid = threadIdx.x;
    const int pk  = bid & 7;

    // ---- occupancy limiter: 96KB LDS pad -> exactly 1 block/CU ----
    __shared__ float pad_lds[24576];
    if (gemm_done == recur_prog) {   // never true at runtime; not provable at compile time
        ((volatile float*)pad_lds)[tid] = 1.0f;
    }

    if (pk < 2) {
        // ---------------- recurrence role ----------------
        const int dir = pk;
        const int g   = bid >> 3;            // 0..31
        const float* whh = dir ? whh_b : whh_f;
        float* hout      = dir ? hb : hf;
        unsigned long long* ex = dir ? (exf + 1024) : exf;

        const int w = tid >> 6, lane = tid & 63;
        const int G = lane >> 4, u = lane & 15;
        const int R = 512 * G + 16 * g + u;  // gate row (wave-independent)

        // wave w holds K-chunk [128w,128w+128) of gate row R in regs
        float wreg[128];
        {
            const float* src = &whh[(size_t)R * HID + w * 128];
            #pragma unroll
            for (int j = 0; j < 32; ++j) {
                float4 v = *(const float4*)&src[j * 4];
                wreg[j*4+0]=v.x; wreg[j*4+1]=v.y; wreg[j*4+2]=v.z; wreg[j*4+3]=v.w;
            }
        }

        __shared__ __align__(16) float h_lds[512];      // wave-private slices
        __shared__ __align__(16) float p_lds[2][256];   // parity; slots 64..255 used
        __shared__ int cntl[8];                          // [par][wave] seq flags
        __shared__ int deadf;

        if (tid < 8) cntl[tid] = -1;
        if (tid == 8) deadf = 0;
        __syncthreads();   // the ONLY barrier in the recurrence role

        volatile int* vcnt  = (volatile int*)cntl;
        volatile int* vdead = (volatile int*)&deadf;

        float cst = 0.f;
        if (w == 0 && lane < 16) cst = c0[dir * HID + 16 * g + lane];

        {   // step-0 h from h0; each wave fills its own slice
            const int i0 = 128 * w + 2 * lane;
            h_lds[i0]     = h0[dir * HID + i0];
            h_lds[i0 + 1] = h0[dir * HID + i0 + 1];
        }

        int dead = 0;
        const float* Zd = Zbuf + (size_t)dir * 2 * CSTEPS * G4;
        float zr_cur = 0.f, zr_pref = 0.f;

        for (int s = 0; s < T_STEPS; ++s) {
            const int par = s & 1;

            if (w == 1) {                       // only wave 1 touches Z
                if ((s & (CSTEPS - 1)) == 0) {  // chunk gate
                    const int cg = s >> 10;
                    int guard = 0; unsigned int gd;
                    for (;;) {
                        gd = __hip_atomic_load(&gemm_done[cg], __ATOMIC_RELAXED,
                                               __HIP_MEMORY_SCOPE_AGENT);
                        if (gd >= (unsigned)NGEMMB) break;
                        __builtin_amdgcn_s_sleep(2);
                        if (++guard > (1 << 16)) { dead = 1; break; }
                    }
                    const int rr = dir ? (1023 - (s & 1023)) : (s & 1023);
                    zr_cur = __hip_atomic_load(
                        &Zd[((size_t)((s >> 10) & 1) * CSTEPS + rr) * G4 + R],
                        __ATOMIC_RELAXED, __HIP_MEMORY_SCOPE_AGENT);
                } else {
                    zr_cur = zr_pref;           // prefetched last step
                }
            }

            if (s > 0) {                        // per-wave poll of own 128-slice
                const int i0   = 128 * w + 2 * lane;
                const int base = par * 512 + i0;
                const unsigned long long want = (unsigned long long)(unsigned)s;
                unsigned long long v0, v1;
                int guard = 0;
                for (;;) {
                    v0 = __hip_atomic_load(&ex[base],     __ATOMIC_RELAXED, __HIP_MEMORY_SCOPE_AGENT);
                    v1 = __hip_atomic_load(&ex[base + 1], __ATOMIC_RELAXED, __HIP_MEMORY_SCOPE_AGENT);
                    if (((v0 >> 32) == want) & ((v1 >> 32) == want)) break;
                    if ((++guard & 63) == 0) {
                        if (*vdead) { dead = 1; break; }
                        if (guard > POLL_GUARD) { *vdead = 1; dead = 1; break; }
                    }
                }
                union { unsigned int ui; float f; } ca, cb;
                ca.ui = (unsigned int)v0; cb.ui = (unsigned int)v1;
                h_lds[i0]     = ca.f;           // wave-local write->read
                h_lds[i0 + 1] = cb.f;
            }
            if (dead) { *vdead = 1; break; }

            // 4-way split accumulators (short dep chains)
            float a0 = 0.f, a1 = 0.f, a2 = 0.f, a3 = 0.f;
            {
                const float4* h4 = (const float4*)&h_lds[w * 128];
                #pragma unroll
                for (int j = 0; j < 8; ++j) {
                    float4 h_0 = h4[4*j+0], h_1 = h4[4*j+1], h_2 = h4[4*j+2], h_3 = h4[4*j+3];
                    a0 += wreg[16*j+ 0]*h_0.x + wreg[16*j+ 1]*h_0.y + wreg[16*j+ 2]*h_0.z + wreg[16*j+ 3]*h_0.w;
                    a1 += wreg[16*j+ 4]*h_1.x + wreg[16*j+ 5]*h_1.y + wreg[16*j+ 6]*h_1.z + wreg[16*j+ 7]*h_1.w;
                    a2 += wreg[16*j+ 8]*h_2.x + wreg[16*j+ 9]*h_2.y + wreg[16*j+10]*h_2.z + wreg[16*j+11]*h_2.w;
                    a3 += wreg[16*j+12]*h_3.x + wreg[16*j+13]*h_3.y + wreg[16*j+14]*h_3.z + wreg[16*j+15]*h_3.w;
                }
            }
            float acc = (a0 + a1) + (a2 + a3);

            if (w != 0) {
                if (w == 1) {
                    acc += zr_cur;              // fold Z (R same per lane)
                    if (((s + 1) & (CSTEPS - 1)) != 0) {   // prefetch next Z
                        const int sn = s + 1;
                        const int rr = dir ? (1023 - (sn & 1023)) : (sn & 1023);
                        zr_pref = __hip_atomic_load(
                            &Zd[((size_t)((sn >> 10) & 1) * CSTEPS + rr) * G4 + R],
                            __ATOMIC_RELAXED, __HIP_MEMORY_SCOPE_AGENT);
                    }
                }
                p_lds[par][64 * w + lane] = acc;
                asm volatile("s_waitcnt lgkmcnt(0)" ::: "memory");
                if (lane == 0) vcnt[par * 4 + w] = s;   // seq flag
                // loop on: next h-poll overlaps wave0's reduce+publish
            } else {
                // wave 0: own partial in regs; wait peers via LDS flags
                int guard = 0;
                for (;;) {
                    int c1 = vcnt[par * 4 + 1];
                    int c2 = vcnt[par * 4 + 2];
                    int c3 = vcnt[par * 4 + 3];
                    if ((c1 == s) & (c2 == s) & (c3 == s)) break;
                    if ((++guard & 63) == 0) {
                        if (*vdead) { dead = 1; break; }
                        if (guard > (1 << 16)) { *vdead = 1; dead = 1; break; }
                    }
                }
                if (dead) break;
                float rv = acc + p_lds[par][64 + lane]
                         + p_lds[par][128 + lane] + p_lds[par][192 + lane];
                float a = (G == 2) ? tanh_fast(rv) : sigm_fast(rv);
                float ig = __shfl(a, u,      64);
                float fg = __shfl(a, u + 16, 64);
                float gg = __shfl(a, u + 32, 64);
                float og = __shfl(a, u + 48, 64);
                if (lane < 16) {
                    float cn = fg * cst + ig * gg;
                    cst = cn;
                    float hn = og * tanh_fast(cn);
                    union { float f; unsigned int ui; } cv; cv.f = hn;
                    unsigned long long pv =
                        ((unsigned long long)(unsigned)(s + 1) << 32) | (unsigned long long)cv.ui;
                    __hip_atomic_store(&ex[((s + 1) & 1) * 512 + 16 * g + lane], pv,
                                       __ATOMIC_RELAXED, __HIP_MEMORY_SCOPE_AGENT);
                    const int t = dir ? (T_STEPS - 1 - s) : s;
                    hout[(size_t)t * HID + 16 * g + lane] = hn;
                }
                if ((s & (CSTEPS - 1)) == (CSTEPS - 1) && lane == 0)
                    __hip_atomic_fetch_add(&recur_prog[s >> 10], 1u, __ATOMIC_RELAXED,
                                           __HIP_MEMORY_SCOPE_AGENT);
            }
        }
        if (dead) *vdead = 1;
    } else if (pk < 6) {
        // ---------------- GEMM producer role (128 blocks) ----------------
        const int gb = (pk - 2) * 32 + (bid >> 3);   // 0..127
        __shared__ __align__(16) float As[16][68];
        __shared__ __align__(16) float Bs[16][68];
        const int lr = tid >> 2, ls = tid & 3, tx = tid & 15, ty = tid >> 4;

        for (int cc = 0; cc < NCHUNK; ++cc) {
            if (cc >= 2 && tid == 0) {          // ring backpressure (sleepy spin)
                int guard = 0; unsigned int rp;
                for (;;) {
                    rp = __hip_atomic_load(&recur_prog[cc - 2], __ATOMIC_RELAXED,
                                           __HIP_MEMORY_SCOPE_AGENT);
                    if (rp >= 64u) break;
                    __builtin_amdgcn_s_sleep(16);
                    if (++guard > (1 << 14)) break;
                }
            }
            __syncthreads();

            for (int tix = gb; tix < 2 * 16 * 32; tix += NGEMMB) {
                const int dr  = tix >> 9;
                const int rem = tix & 511;
                const int mt  = rem >> 5;
                const int nt  = rem & 31;
                const int t0  = dr ? (T_STEPS - (cc + 1) * CSTEPS) : (cc * CSTEPS);
                const float* W  = dr ? wih_b : wih_f;
                const float* bi = dr ? bih_b : bih_f;
                const float* bh = dr ? bhh_b : bhh_f;
                float* Zt = Zbuf + (size_t)(dr * 2 + (cc & 1)) * CSTEPS * G4;

                float acc[4][4] = {};
                for (int k0 = 0; k0 < DMODEL; k0 += 16) {
                    float4 av = *(const float4*)&seq[(size_t)(t0 + mt*64 + lr) * DMODEL + k0 + ls*4];
                    float4 bv = *(const float4*)&W[(size_t)(nt*64 + lr) * DMODEL + k0 + ls*4];
                    __syncthreads();
                    As[ls*4+0][lr]=av.x; As[ls*4+1][lr]=av.y; As[ls*4+2][lr]=av.z; As[ls*4+3][lr]=av.w;
                    Bs[ls*4+0][lr]=bv.x; Bs[ls*4+1][lr]=bv.y; Bs[ls*4+2][lr]=bv.z; Bs[ls*4+3][lr]=bv.w;
                    __syncthreads();
                    #pragma unroll
                    for (int k = 0; k < 16; ++k) {
                        float4 a = *(const float4*)&As[k][ty * 4];
                        float4 b = *(const float4*)&Bs[k][tx * 4];
                        acc[0][0]+=a.x*b.x; acc[0][1]+=a.x*b.y; acc[0][2]+=a.x*b.z; acc[0][3]+=a.x*b.w;
                        acc[1][0]+=a.y*b.x; acc[1][1]+=a.y*b.y; acc[1][2]+=a.y*b.z; acc[1][3]+=a.y*b.w;
                        acc[2][0]+=a.z*b.x; acc[2][1]+=a.z*b.y; acc[2][2]+=a.z*b.z; acc[2][3]+=a.z*b.w;
                        acc[3][0]+=a.w*b.x; acc[3][1]+=a.w*b.y; acc[3][2]+=a.w*b.z; acc[3][3]+=a.w*b.w;
                    }
                }
                float4 b4  = *(const float4*)&bi[nt * 64 + tx * 4];
                float4 c4v = *(const float4*)&bh[nt * 64 + tx * 4];
                float bx=b4.x+c4v.x, by=b4.y+c4v.y, bz=b4.z+c4v.z, bw_=b4.w+c4v.w;
                #pragma unroll
                for (int i = 0; i < 4; ++i) {
                    float4 o;
                    o.x=acc[i][0]+bx; o.y=acc[i][1]+by; o.z=acc[i][2]+bz; o.w=acc[i][3]+bw_;
                    *(float4*)&Zt[(size_t)(mt*64 + ty*4 + i) * G4 + nt*64 + tx*4] = o;
                }
            }
            __threadfence();                    // drain Z before signaling
            __syncthreads();
            if (tid == 0)
                __hip_atomic_fetch_add(&gemm_done[cc], 1u, __ATOMIC_RELEASE,
                                       __HIP_MEMORY_SCOPE_AGENT);
        }
    }
    // pk 6,7: exit immediately
}

// =====================================================================
__global__ __launch_bounds__(256) void feats_kernel(
    const float* __restrict__ hf, const float* __restrict__ hb,
    const float* __restrict__ wlin, const float* __restrict__ blin,
    float* __restrict__ feats)
{
    const int t = blockIdx.x;
    __shared__ __align__(16) float hl[1024];
    const int tid = threadIdx.x;
    {
        const float* src = (tid < 128) ? &hf[(size_t)t * HID + tid * 4]
                                       : &hb[(size_t)t * HID + (tid - 128) * 4];
        *(float4*)&hl[tid * 4] = *(const float4*)src;
    }
    __syncthreads();
    const int c = tid >> 4, p = tid & 15;
    float s = 0.0f;
    #pragma unroll
    for (int j = 0; j < 16; ++j) {
        float4 h4 = *(const float4*)&hl[p * 4 + j * 64];
        float4 w4 = *(const float4*)&wlin[(size_t)c * 1024 + p * 4 + j * 64];
        s += h4.x*w4.x + h4.y*w4.y + h4.z*w4.z + h4.w*w4.w;
    }
    s += __shfl_down(s, 8, 16);
    s += __shfl_down(s, 4, 16);
    s += __shfl_down(s, 2, 16);
    s += __shfl_down(s, 1, 16);
    if (p == 0) feats[t * NC + c] = s + blin[c];
}

// =====================================================================
// Viterbi forward, single wave. Tree-max rewrite: fmax is EXACT, so the
// max value is bit-identical to the sequential strict-> chain; picking
// the smallest index attaining it reproduces np.argmax first-max.
// ~150cy/step vs ~350cy for the serial compare chain.
// =====================================================================
__global__ __launch_bounds__(64) void viterbi_kernel(
    const float* __restrict__ feats, const float* __restrict__ trans,
    unsigned char* __restrict__ bp, float* __restrict__ out,
    unsigned int* __restrict__ bT)
{
    __shared__ __align__(16) float fl[4096];
    __shared__ __align__(16) float fvs[16];
    const int l = threadIdx.x;
    float tr[16];
    if (l < 16) {
        #pragma unroll
        for (int j = 0; j < 16; ++j) tr[j] = trans[l * 16 + j];
    }
    float fv = 0.0f;
    for (int cb = 0; cb < 64; ++cb) {
        #pragma unroll
        for (int j = 0; j < 16; ++j)
            *(float4*)&fl[j * 256 + l * 4] =
                *(const float4*)&feats[cb * 4096 + j * 256 + l * 4];
        __syncthreads();
        if (l < 16) {
            for (int k = 0; k < 256; ++k) {
                float sc[16];
                #pragma unroll
                for (int j = 0; j < 16; ++j)
                    sc[j] = __shfl(fv, j, 16) + tr[j];
                // exact tree max (fmax has no rounding)
                float m0 = fmaxf(fmaxf(fmaxf(sc[0],  sc[1]),  fmaxf(sc[2],  sc[3])),
                                 fmaxf(fmaxf(sc[4],  sc[5]),  fmaxf(sc[6],  sc[7])));
                float m1 = fmaxf(fmaxf(fmaxf(sc[8],  sc[9]),  fmaxf(sc[10], sc[11])),
                                 fmaxf(fmaxf(sc[12], sc[13]), fmaxf(sc[14], sc[15])));
                float m = fmaxf(m0, m1);
                // first index attaining the max (np.argmax semantics)
                int bi = 15;
                #pragma unroll
                for (int j = 15; j >= 0; --j)
                    if (sc[j] == m) bi = j;
                bp[(size_t)(cb * 256 + k) * 16 + l] = (unsigned char)bi;
                fv = m + fl[k * 16 + l];
            }
        }
        __syncthreads();
    }
    if (l < 16) fvs[l] = fv;
    __syncthreads();
    if (l == 0) {
        float best = fvs[0]; int bi = 0;
        #pragma unroll
        for (int j = 1; j < 16; ++j) if (fvs[j] > best) { best = fvs[j]; bi = j; }
        out[0] = best;
        out[1 + T_STEPS] = (float)bi;
        *bT = (unsigned int)bi;
    }
}

// =====================================================================
__global__ __launch_bounds__(64) void maps_kernel(
    const unsigned char* __restrict__ bp, unsigned char* __restrict__ P)
{
    const int j = blockIdx.x;
    const int l = threadIdx.x;
    __shared__ __align__(16) unsigned char lb[4096];
    __shared__ __align__(16) unsigned char lp[4096];
    #pragma unroll
    for (int i = 0; i < 4; ++i)
        *(uint4*)&lb[i * 1024 + l * 16] = *(const uint4*)&bp[(size_t)j * 4096 + i * 1024 + l * 16];
    __syncthreads();
    if (l < 16) {
        int cur = l;
        for (int k = 255; k >= 0; --k) {
            cur = lb[k * 16 + cur];
            lp[k * 16 + l] = (unsigned char)cur;
        }
    }
    __syncthreads();
    #pragma unroll
    for (int i = 0; i < 4; ++i)
        *(uint4*)&P[(size_t)j * 4096 + i * 1024 + l * 16] = *(const uint4*)&lp[i * 1024 + l * 16];
}

// =====================================================================
__global__ __launch_bounds__(64) void path_kernel(
    const unsigned char* __restrict__ P, const unsigned int* __restrict__ bT,
    float* __restrict__ out)
{
    const int j = blockIdx.x;
    const int l = threadIdx.x;
    int e = (int)(*bT);
    for (int i = 63; i > j; --i) e = P[(size_t)i * 4096 + e];
    for (int k = l; k < 256; k += 64)
        out[1 + j * 256 + k] = (float)P[(size_t)j * 4096 + k * 16 + e];
}

__global__ void fb_kernel(float* out, int n, float v0) {
    int i = blockIdx.x * 256 + threadIdx.x;
    if (i < n) out[i] = (i == 0) ? v0 : 0.0f;
}

extern "C" void kernel_launch(void* const* d_in, const int* in_sizes, int n_in,
                              void* d_out, int out_size, void* d_ws, size_t ws_size,
                              hipStream_t stream) {
    const float* seq   = (const float*)d_in[0];
    const float* h0    = (const float*)d_in[1];
    const float* c0    = (const float*)d_in[2];
    const float* wih_f = (const float*)d_in[3];
    const float* whh_f = (const float*)d_in[4];
    const float* bih_f = (const float*)d_in[5];
    const float* bhh_f = (const float*)d_in[6];
    const float* wih_b = (const float*)d_in[7];
    const float* whh_b = (const float*)d_in[8];
    const float* bih_b = (const float*)d_in[9];
    const float* bhh_b = (const float*)d_in[10];
    const float* wlin  = (const float*)d_in[11];
    const float* blin  = (const float*)d_in[12];
    const float* trans = (const float*)d_in[13];
    float* out = (float*)d_out;

    if (ws_size < NEED_B) {
        fb_kernel<<<(out_size + 255) / 256, 256, 0, stream>>>(out, out_size, -(float)ws_size);
        return;
    }

    float* wsf = (float*)d_ws;
    float* Zbuf  = wsf + OFF_Z;
    float* hf    = wsf + OFF_HF;
    float* hb    = wsf + OFF_HB;
    float* feats = wsf + OFF_FEATS;
    unsigned char* bp = (unsigned char*)d_ws + OFF_BP_B;
    unsigned char* P  = (unsigned char*)d_ws + OFF_P_B;
    unsigned long long* exf = (unsigned long long*)((char*)d_ws + OFF_EX_B);
    unsigned int* ctr = (unsigned int*)((char*)d_ws + OFF_CTR_B);
    unsigned int* gemm_done  = ctr;          // [16]
    unsigned int* recur_prog = ctr + 16;     // [16]
    unsigned int* bT         = ctr + 32;

    // zero exchange tags + counters each call (replay determinism)
    hipMemsetAsync((void*)exf, 0, 16384 + 1024, stream);

    {
        void* args[] = { (void*)&seq,
                         (void*)&wih_f, (void*)&bih_f, (void*)&bhh_f,
                         (void*)&wih_b, (void*)&bih_b, (void*)&bhh_b,
                         (void*)&whh_f, (void*)&whh_b,
                         (void*)&h0, (void*)&c0,
                         (void*)&hf, (void*)&hb, (void*)&Zbuf,
                         (void*)&exf,
                         (void*)&gemm_done, (void*)&recur_prog };
        hipError_t e = hipLaunchCooperativeKernel(
            reinterpret_cast<void*>(fused_kernel), dim3(256), dim3(256),
            args, 0, stream);
        if (e != hipSuccess) {
            fused_kernel<<<256, 256, 0, stream>>>(
                seq, wih_f, bih_f, bhh_f, wih_b, bih_b, bhh_b,
                whh_f, whh_b, h0, c0, hf, hb, Zbuf, exf,
                gemm_done, recur_prog);
        }
    }

    feats_kernel<<<16384, 256, 0, stream>>>(hf, hb, wlin, blin, feats);
    viterbi_kernel<<<1, 64, 0, stream>>>(feats, trans, bp, out, bT);
    maps_kernel<<<64, 64, 0, stream>>>(bp, P);
    path_kernel<<<64, 64, 0, stream>>>(P, bT, out);
}